// Round 7
// baseline (122.812 us; speedup 1.0000x reference)
//
#include <hip/hip_runtime.h>

// Shapes from reference: n=32, p2=49, topk=4, w2=64, c_kv=256
// out[b,p,t,w,c] = r_weight[b,p,t] * kv[b, r_idx[b,p,t], w, c]
constexpr int N    = 32;
constexpr int P2   = 49;
constexpr int TOPK = 4;
constexpr int W2   = 64;
constexpr int CKV  = 256;
constexpr int ROW  = W2 * CKV;       // 16384 floats per gathered slab (64 KB)
constexpr int ROW4 = ROW / 4;        // 4096 float4 per slab
constexpr int G    = N * P2 * TOPK;  // 6272 (b,p,t) tuples
constexpr int HALF4 = ROW4 / 2;      // 2048 float4 per half-slab (32 KB)
constexpr int NH   = G * 2;          // 12544 half-slabs
constexpr int NBLK = 1792;           // 7 blocks/CU; NH/NBLK = 7 exactly (no tail)
constexpr int ITERS = NH / NBLK;     // 7 half-slabs per block, perfectly balanced

typedef float floatx4 __attribute__((ext_vector_type(4)));

__global__ __launch_bounds__(256)
void kv_gather_scale(const int* __restrict__ r_idx,
                     const float* __restrict__ r_weight,
                     const float* __restrict__ kv,
                     float* __restrict__ out) {
    const floatx4* __restrict__ kv4  = (const floatx4*)kv;
    floatx4* __restrict__       out4 = (floatx4*)out;

    // Persistent grid-stride over half-slabs in LINEAR order (the order R1
    // proved best): block handles h, h+1792, ... — the chip-wide instantaneous
    // store window stays a contiguous ~56 MB band.
    int   h   = blockIdx.x;
    int   g   = h >> 1;
    int   src = r_idx[g];
    float w   = r_weight[g];

    #pragma unroll 1
    for (int it = 0; it < ITERS; ++it) {
        // Prefetch next iteration's index/weight so the scalar-load latency
        // hides under this iteration's 32 KB copy.
        const int hn = h + NBLK;
        const int gn = hn >> 1;
        int   srcn = 0;
        float wn   = 0.f;
        if (it + 1 < ITERS) { srcn = r_idx[gn]; wn = r_weight[gn]; }

        const int b   = g / (P2 * TOPK);
        const int off = (h & 1) * HALF4;
        const floatx4* __restrict__ s =
            kv4 + (size_t)(b * P2 + src) * ROW4 + off;
        floatx4* __restrict__ d = out4 + (size_t)g * ROW4 + off;

        #pragma unroll
        for (int i = threadIdx.x; i < HALF4; i += 256) {
            d[i] = s[i] * w;
        }

        h = hn; g = gn; src = srcn; w = wn;
    }
}

extern "C" void kernel_launch(void* const* d_in, const int* in_sizes, int n_in,
                              void* d_out, int out_size, void* d_ws, size_t ws_size,
                              hipStream_t stream) {
    const int*   r_idx    = (const int*)d_in[0];
    const float* r_weight = (const float*)d_in[1];
    const float* kv       = (const float*)d_in[2];
    float*       out      = (float*)d_out;

    kv_gather_scale<<<NBLK, 256, 0, stream>>>(r_idx, r_weight, kv, out);
}

// Round 8
// 109.658 us; speedup vs baseline: 1.1200x; 1.1200x over previous
//
#include <hip/hip_runtime.h>

// Shapes from reference: n=32, p2=49, topk=4, w2=64, c_kv=256
// out[b,p,t,w,c] = r_weight[b,p,t] * kv[b, r_idx[b,p,t], w, c]
constexpr int N    = 32;
constexpr int P2   = 49;
constexpr int TOPK = 4;
constexpr int W2   = 64;
constexpr int CKV  = 256;
constexpr int ROW  = W2 * CKV;      // 16384 floats per gathered slab (64 KB)
constexpr int ROW4 = ROW / 4;       // 4096 float4 per slab
constexpr int NBLK = N * P2 * TOPK; // 6272 blocks, one slab each (R1 mapping)

typedef float floatx4 __attribute__((ext_vector_type(4)));

__global__ __launch_bounds__(256)
void kv_gather_scale(const int* __restrict__ r_idx,
                     const float* __restrict__ r_weight,
                     const float* __restrict__ kv,
                     float* __restrict__ out) {
    const int g = blockIdx.x;                 // flat (b, p, t)
    const int b = g / (P2 * TOPK);

    const int   src = r_idx[g];               // source p-row in [0, P2)
    const float w   = r_weight[g];

    const floatx4* __restrict__ s =
        (const floatx4*)(kv + (size_t)(b * P2 + src) * ROW);
    floatx4* __restrict__ d = (floatx4*)(out + (size_t)g * ROW);

    // Burst-segregated copy: per wave, 8 independent loads issue back-to-back
    // (8 KB pure-read burst), drain, then 8 stores back-to-back (8 KB pure-
    // write burst). Goal: give the HBM controller long unidirectional bursts
    // instead of fine-grained read/write interleave (turnaround cost).
    // 8 float4 live = 32 data VGPRs -> keeps 8 waves/SIMD residency.
    #pragma unroll 1
    for (int half = 0; half < 2; ++half) {
        const int base = half * 8 * 256 + threadIdx.x;
        floatx4 v[8];
        #pragma unroll
        for (int j = 0; j < 8; ++j) {
            v[j] = s[base + j * 256];
        }
        #pragma unroll
        for (int j = 0; j < 8; ++j) {
            d[base + j * 256] = v[j] * w;
        }
    }
}

extern "C" void kernel_launch(void* const* d_in, const int* in_sizes, int n_in,
                              void* d_out, int out_size, void* d_ws, size_t ws_size,
                              hipStream_t stream) {
    const int*   r_idx    = (const int*)d_in[0];
    const float* r_weight = (const float*)d_in[1];
    const float* kv       = (const float*)d_in[2];
    float*       out      = (float*)d_out;

    kv_gather_scale<<<NBLK, 256, 0, stream>>>(r_idx, r_weight, kv, out);
}

// Round 9
// 108.251 us; speedup vs baseline: 1.1345x; 1.0130x over previous
//
#include <hip/hip_runtime.h>

// Shapes from reference: n=32, p2=49, topk=4, w2=64, c_kv=256
// out[b,p,t,w,c] = r_weight[b,p,t] * kv[b, r_idx[b,p,t], w, c]
//
// Final form (R1): one 64 KB slab per block, linear block order, plain cached
// loads+stores. Probed and rejected: coarser grain (-32%), finer grain (-4%),
// XCD-chunked swizzle (-17%), nontemporal stores (-4%), persistent balanced
// grid (-13%), read/write burst segregation (0%). 514 MB compulsory traffic
// in ~108 us = 4.74 TB/s — the empirical ceiling for this 1:4 read:write
// gather mix on MI355X.
constexpr int N    = 32;
constexpr int P2   = 49;
constexpr int TOPK = 4;
constexpr int W2   = 64;
constexpr int CKV  = 256;
constexpr int ROW  = W2 * CKV;      // 16384 floats per gathered slab (64 KB)
constexpr int ROW4 = ROW / 4;       // 4096 float4 per slab

__global__ __launch_bounds__(256)
void kv_gather_scale(const int* __restrict__ r_idx,
                     const float* __restrict__ r_weight,
                     const float* __restrict__ kv,
                     float* __restrict__ out) {
    const int g = blockIdx.x;                 // flat (b, p, t) in [0, N*P2*TOPK)
    const int b = g / (P2 * TOPK);

    const int   src = r_idx[g];               // source p-row in [0, P2)
    const float w   = r_weight[g];

    const float4* __restrict__ s =
        (const float4*)(kv + (size_t)(b * P2 + src) * ROW);
    float4* __restrict__ d = (float4*)(out + (size_t)g * ROW);

    #pragma unroll 4
    for (int i = threadIdx.x; i < ROW4; i += 256) {
        float4 v = s[i];
        v.x *= w; v.y *= w; v.z *= w; v.w *= w;
        d[i] = v;
    }
}

extern "C" void kernel_launch(void* const* d_in, const int* in_sizes, int n_in,
                              void* d_out, int out_size, void* d_ws, size_t ws_size,
                              hipStream_t stream) {
    const int*   r_idx    = (const int*)d_in[0];
    const float* r_weight = (const float*)d_in[1];
    const float* kv       = (const float*)d_in[2];
    float*       out      = (float*)d_out;

    const int nblocks = N * P2 * TOPK;        // 6272
    kv_gather_scale<<<nblocks, 256, 0, stream>>>(r_idx, r_weight, kv, out);
}